// Round 16
// baseline (291.148 us; speedup 1.0000x reference)
//
#include <hip/hip_runtime.h>
#include <cstdint>
#include <cstddef>

#define NB 16
#define NL 2048
#define ND 64
#define QT 16                 // q rows per workgroup
#define NW 8                  // waves per workgroup
#define NTHREADS (NW * 64)
#define SLICE (NL / NW)       // 256 k-cols per wave
#define NT (SLICE / 16)       // 16 MFMA col-tiles per wave
#define ROWU 1026             // u32 per padded LDS row (4104 B)
#define ELSU (QT * ROWU)      // 16416 u32 = 65664 B
#define LDSB (ELSU * 4)
#define QEC (NB * NL * ND)    // 2M elems per q/k/v matrix

typedef __attribute__((ext_vector_type(8))) short bf16x8;
typedef __attribute__((ext_vector_type(4))) float f32x4;
typedef __attribute__((ext_vector_type(4))) int i32x4;
typedef __attribute__((ext_vector_type(4))) unsigned short u16x4;
typedef __attribute__((ext_vector_type(2))) unsigned int u32x2;
typedef __attribute__((ext_vector_type(4))) unsigned int u32x4;
typedef unsigned short u16;

#define MFMA __builtin_amdgcn_mfma_f32_16x16x32_bf16

__device__ __forceinline__ u16 f2bf(float x) {
  union { float f; uint32_t u; } v; v.f = x;
  uint32_t r = v.u + 0x7FFFu + ((v.u >> 16) & 1u);   // RNE
  return (u16)(r >> 16);
}
__device__ __forceinline__ float bfhi2f(uint32_t w) {
  union { uint32_t u; float f; } v; v.u = w & 0xFFFF0000u; return v.f;
}
__device__ __forceinline__ float bflo2f(uint32_t w) {
  union { uint32_t u; float f; } v; v.u = w << 16; return v.f;
}
// XOR-swizzle byte offset within a 4096B LDS row (keeps 16B alignment)
__device__ __forceinline__ int swzb(int cb) { return cb ^ (((cb >> 7) & 7) << 4); }

// mask nibble (fallback path). MODE: 0=i32,1=u8,2=f32,3=i64
template <int MODE>
__device__ __forceinline__ uint32_t mnib(const void* __restrict__ m, size_t i) {
  if constexpr (MODE == 1) {
    const uint32_t x = __builtin_nontemporal_load((const uint32_t*)((const uint8_t*)m + i));
    return (x | (x >> 7) | (x >> 14) | (x >> 21)) & 0xFu;
  } else if constexpr (MODE == 0) {
    const i32x4 x = __builtin_nontemporal_load(((const i32x4*)((const int*)m + i)));
    return (uint32_t)(x[0] != 0) | ((uint32_t)(x[1] != 0) << 1) |
           ((uint32_t)(x[2] != 0) << 2) | ((uint32_t)(x[3] != 0) << 3);
  } else if constexpr (MODE == 2) {
    const f32x4 x = __builtin_nontemporal_load(((const f32x4*)((const float*)m + i)));
    return (uint32_t)(x[0] != 0.f) | ((uint32_t)(x[1] != 0.f) << 1) |
           ((uint32_t)(x[2] != 0.f) << 2) | ((uint32_t)(x[3] != 0.f) << 3);
  } else {
    const uint32_t* p = (const uint32_t*)m + 2 * i;
    return (uint32_t)(p[0] != 0u) | ((uint32_t)(p[2] != 0u) << 1) |
           ((uint32_t)(p[4] != 0u) << 2) | ((uint32_t)(p[6] != 0u) << 3);
  }
}

template <bool WS>
__device__ __forceinline__ void loadKfrag(const float* __restrict__ k,
                                          const u16* __restrict__ kb,
                                          int b, int row, int kg,
                                          bf16x8& b0, bf16x8& b1) {
  if constexpr (WS) {
    const u16* kp = kb + ((size_t)(b * NL + row)) * ND + kg * 8;
    b0 = *(const bf16x8*)kp;
    b1 = *(const bf16x8*)(kp + 32);
  } else {
    const float* kp = k + ((size_t)(b * NL + row)) * ND + kg * 8;
#pragma unroll
    for (int i = 0; i < 8; ++i) {
      b0[i] = (short)f2bf(kp[i]);
      b1[i] = (short)f2bf(kp[i + 32]);
    }
  }
}

// ---------------- Split path: K1 = QK^T + exp -> e_ws + inv ----------------
__global__ void __launch_bounds__(NTHREADS, 4)
attn_e(const u16* __restrict__ qs, const u16* __restrict__ kb,
       const uint32_t* __restrict__ mb,
       u16* __restrict__ ews, float* __restrict__ invw) {
  extern __shared__ uint32_t els[];
  __shared__ float rsums[NW * QT];
  const int tid = threadIdx.x;
  const int lane = tid & 63;
  const int w = tid >> 6;
  const int fr = lane & 15;
  const int kg = lane >> 4;

  const int bid = blockIdx.x;
  const int swzid = (bid & 7) * ((NB * (NL / QT)) / 8) + (bid >> 3);
  const int b = swzid >> 7;
  const int q0 = (swzid & 127) * QT;
  const int cbase = w * SLICE;
  const size_t bq = (size_t)b * NL + q0;

  // Q fragments
  const u16* qp = qs + (bq + fr) * ND + kg * 8;
  const bf16x8 a0 = *(const bf16x8*)qp;
  const bf16x8 a1 = *(const bf16x8*)(qp + 32);

  // mask bit-words
  uint32_t mw[8];
  const uint32_t* mbr = mb + (bq + fr) * (NL / 32) + (cbase >> 5);
#pragma unroll
  for (int u = 0; u < 8; ++u) mw[u] = mbr[u];

  float rs = 0.f;
#pragma unroll
  for (int ti = 0; ti < NT; ++ti) {
    const int c0 = cbase + ti * 16;
    bf16x8 b0, b1;
    loadKfrag<true>(nullptr, kb, b, c0 + fr, kg, b0, b1);
    f32x4 s = {0.f, 0.f, 0.f, 0.f};
    s = MFMA(b0, a0, s, 0, 0, 0);
    s = MFMA(b1, a1, s, 0, 0, 0);
    const uint32_t nib = (mw[ti >> 1] >> (16 * (ti & 1) + 4 * kg)) & 0xFu;
    const float e0 = (nib & 1u) ? 0.f : __expf(s[0]);
    const float e1 = (nib & 2u) ? 0.f : __expf(s[1]);
    const float e2 = (nib & 4u) ? 0.f : __expf(s[2]);
    const float e3 = (nib & 8u) ? 0.f : __expf(s[3]);
    rs += (e0 + e1) + (e2 + e3);
    u32x2 ep;
    ep[0] = (uint32_t)f2bf(e0) | ((uint32_t)f2bf(e1) << 16);
    ep[1] = (uint32_t)f2bf(e2) | ((uint32_t)f2bf(e3) << 16);
    *(u32x2*)(els + fr * ROWU + (swzb((c0 + 4 * kg) * 2) >> 2)) = ep;
  }
  rs += __shfl_xor(rs, 16, 64);
  rs += __shfl_xor(rs, 32, 64);
  if (lane < 16) rsums[w * QT + fr] = rs;
  __syncthreads();

  float invf = 0.f;
#pragma unroll
  for (int ww = 0; ww < NW; ++ww) invf += rsums[ww * QT + fr];
  invf = 1.0f / invf;
  if (w == 0 && lane < 16) invw[bq + fr] = invf;

  // coalesced e writeout: own col slice, all 16 rows (512B/wave-instr)
  const int lofs = swzb((cbase + 4 * lane) * 2) >> 2;
  u16* eb = ews + bq * NL + cbase + 4 * lane;
#pragma unroll
  for (int r = 0; r < 16; ++r) {
    const u32x2 el = *(const u32x2*)(els + r * ROWU + lofs);
    __builtin_nontemporal_store(el, (u32x2*)(eb + (size_t)r * NL));
  }
}

// ---------------- Split path: K2 = stream (e*inv*ew -> attn) + PV ----------------
__global__ void __launch_bounds__(NTHREADS, 4)
attn_spv(const u16* __restrict__ ews, const float* __restrict__ invw,
         const float* __restrict__ ew, const u16* __restrict__ vt,
         float* __restrict__ out, float* __restrict__ attn) {
  extern __shared__ uint32_t els[];
  const int tid = threadIdx.x;
  const int lane = tid & 63;
  const int w = tid >> 6;
  const int fr = lane & 15;
  const int kg = lane >> 4;

  const int bid = blockIdx.x;
  const int swzid = (bid & 7) * ((NB * (NL / QT)) / 8) + (bid >> 3);
  const int b = swzid >> 7;
  const int q0 = (swzid & 127) * QT;
  const int cbase = w * SLICE;
  const size_t bq = (size_t)b * NL + q0;

  const float invf = invw[bq + fr];   // lane fr holds row fr's inv

  // ---- B1: pure streaming + LDS p-tile fill (own slice, all 16 rows) ----
  const int lofs = swzb((cbase + 4 * lane) * 2) >> 2;
  const u16* eb = ews + bq * NL + cbase + 4 * lane;
  const float* ewb = ew + bq * NL + cbase + 4 * lane;
  float* atb = attn + bq * NL + cbase + 4 * lane;
#pragma unroll
  for (int r = 0; r < 16; ++r) {
    const u32x2 el = __builtin_nontemporal_load((const u32x2*)(eb + (size_t)r * NL));
    const f32x4 w4 = __builtin_nontemporal_load((const f32x4*)(ewb + (size_t)r * NL));
    const float inv_r = __shfl(invf, r, 64);
    f32x4 p;
    p[0] = bflo2f(el[0]) * inv_r * w4[0];
    p[1] = bfhi2f(el[0]) * inv_r * w4[1];
    p[2] = bflo2f(el[1]) * inv_r * w4[2];
    p[3] = bfhi2f(el[1]) * inv_r * w4[3];
    __builtin_nontemporal_store(p, (f32x4*)(atb + (size_t)r * NL));
    u32x2 pp;
    pp[0] = (uint32_t)f2bf(p[0]) | ((uint32_t)f2bf(p[1]) << 16);
    pp[1] = (uint32_t)f2bf(p[2]) | ((uint32_t)f2bf(p[3]) << 16);
    *(u32x2*)(els + r * ROWU + lofs) = pp;
  }

  // ---- B2: PV MFMA from own LDS slice ----
  f32x4 oA[4] = {{0.f,0.f,0.f,0.f},{0.f,0.f,0.f,0.f},{0.f,0.f,0.f,0.f},{0.f,0.f,0.f,0.f}};
#pragma unroll
  for (int gi = 0; gi < NT / 2; ++gi) {
    union { u32x4 u; bf16x8 v8; } pu;
    pu.u = *(const u32x4*)(els + fr * ROWU + (swzb((cbase + 32 * gi + 8 * kg) * 2) >> 2));
    const bf16x8 pa = pu.v8;
    const int kk = cbase + gi * 32 + kg * 8;
    const u16* vp = vt + ((size_t)(b * ND + fr)) * NL + kk;   // VT[d][k]
    oA[0] = MFMA(pa, *(const bf16x8*)(vp),           oA[0], 0, 0, 0);
    oA[1] = MFMA(pa, *(const bf16x8*)(vp + 16 * NL), oA[1], 0, 0, 0);
    oA[2] = MFMA(pa, *(const bf16x8*)(vp + 32 * NL), oA[2], 0, 0, 0);
    oA[3] = MFMA(pa, *(const bf16x8*)(vp + 48 * NL), oA[3], 0, 0, 0);
  }
  __syncthreads();   // all LDS p-reads done; reuse els as out-staging

  float* osta = (float*)els;
  f32x4 acc = {0.f, 0.f, 0.f, 0.f};
  const int rrr = tid >> 4;
  const int d4 = (tid & 15) * 4;
#pragma unroll
  for (int round = 0; round < NW / 2; ++round) {
    if ((w >> 1) == round) {
      float* od = osta + (w & 1) * (QT * ND);
#pragma unroll
      for (int dt = 0; dt < 4; ++dt)
#pragma unroll
        for (int j = 0; j < 4; ++j)
          od[(4 * kg + j) * ND + dt * 16 + fr] = oA[dt][j];
    }
    __syncthreads();
    if (tid < QT * ND / 4) {
      acc += *(const f32x4*)(osta + rrr * ND + d4) +
             *(const f32x4*)(osta + QT * ND + rrr * ND + d4);
    }
    __syncthreads();
  }
  if (tid < QT * ND / 4)
    *(f32x4*)(out + (bq + rrr) * ND + d4) = acc;
}

// ---------------- Fused fallback (R15 behavior) ----------------
template <int MMODE, bool WS>
__device__ __forceinline__ void attn_core(
    const float* __restrict__ q, const float* __restrict__ k,
    const float* __restrict__ v, const float* __restrict__ ew,
    const void* __restrict__ mask,
    const u16* __restrict__ qs, const u16* __restrict__ kb,
    const u16* __restrict__ vt, const uint32_t* __restrict__ mb,
    float* __restrict__ out, float* __restrict__ attn,
    uint32_t* __restrict__ els, float* __restrict__ rsums) {
  const int tid = threadIdx.x;
  const int lane = tid & 63;
  const int w = tid >> 6;
  const int fr = lane & 15;
  const int kg = lane >> 4;

  const int bid = blockIdx.x;
  const int swzid = (bid & 7) * ((NB * (NL / QT)) / 8) + (bid >> 3);
  const int b = swzid >> 7;
  const int q0 = (swzid & 127) * QT;
  const int cbase = w * SLICE;
  const size_t bq = (size_t)b * NL + q0;
  const size_t lrow = bq * NL + (size_t)fr * NL + (size_t)(cbase + 4 * kg);

  bf16x8 a0, a1;
  if constexpr (WS) {
    const u16* qp = qs + (bq + fr) * ND + kg * 8;
    a0 = *(const bf16x8*)qp;
    a1 = *(const bf16x8*)(qp + 32);
  } else {
    const float* qp = q + (bq + fr) * ND + kg * 8;
#pragma unroll
    for (int i = 0; i < 8; ++i) {
      a0[i] = (short)f2bf(qp[i] * 0.125f);
      a1[i] = (short)f2bf(qp[i + 32] * 0.125f);
    }
  }

  uint32_t mw[8];
  if constexpr (WS) {
    const uint32_t* mbr = mb + (bq + fr) * (NL / 32) + (cbase >> 5);
#pragma unroll
    for (int u = 0; u < 8; ++u) mw[u] = mbr[u];
  }

  float rs = 0.f;
#pragma unroll
  for (int ti = 0; ti < NT; ++ti) {
    const int c0 = cbase + ti * 16;
    bf16x8 b0, b1;
    loadKfrag<WS>(k, kb, b, c0 + fr, kg, b0, b1);
    f32x4 s = {0.f, 0.f, 0.f, 0.f};
    s = MFMA(b0, a0, s, 0, 0, 0);
    s = MFMA(b1, a1, s, 0, 0, 0);
    uint32_t nib;
    if constexpr (WS) nib = (mw[ti >> 1] >> (16 * (ti & 1) + 4 * kg)) & 0xFu;
    else              nib = mnib<MMODE>(mask, lrow + (size_t)(ti * 16));
    const float e0 = (nib & 1u) ? 0.f : __expf(s[0]);
    const float e1 = (nib & 2u) ? 0.f : __expf(s[1]);
    const float e2 = (nib & 4u) ? 0.f : __expf(s[2]);
    const float e3 = (nib & 8u) ? 0.f : __expf(s[3]);
    rs += (e0 + e1) + (e2 + e3);
    u32x2 ep;
    ep[0] = (uint32_t)f2bf(e0) | ((uint32_t)f2bf(e1) << 16);
    ep[1] = (uint32_t)f2bf(e2) | ((uint32_t)f2bf(e3) << 16);
    *(u32x2*)(els + fr * ROWU + (swzb((c0 + 4 * kg) * 2) >> 2)) = ep;
  }
  rs += __shfl_xor(rs, 16, 64);
  rs += __shfl_xor(rs, 32, 64);
  if (lane < 16) rsums[w * QT + fr] = rs;
  __syncthreads();

  float invf = 0.f;
#pragma unroll
  for (int ww = 0; ww < NW; ++ww) invf += rsums[ww * QT + fr];
  invf = 1.0f / invf;

  float* atb = attn + bq * NL + cbase + 4 * lane;
  const float* ewb = ew + bq * NL + cbase + 4 * lane;
  const int lofs = swzb((cbase + 4 * lane) * 2) >> 2;
#pragma unroll
  for (int r = 0; r < 16; ++r) {
    const u32x2 el = *(const u32x2*)(els + r * ROWU + lofs);
    const f32x4 w4 = __builtin_nontemporal_load((const f32x4*)(ewb + (size_t)r * NL));
    const float inv_r = __shfl(invf, r, 64);
    f32x4 p;
    p[0] = bflo2f(el[0]) * inv_r * w4[0];
    p[1] = bfhi2f(el[0]) * inv_r * w4[1];
    p[2] = bflo2f(el[1]) * inv_r * w4[2];
    p[3] = bfhi2f(el[1]) * inv_r * w4[3];
    __builtin_nontemporal_store(p, (f32x4*)(atb + (size_t)r * NL));
    u32x2 pp;
    pp[0] = (uint32_t)f2bf(p[0]) | ((uint32_t)f2bf(p[1]) << 16);
    pp[1] = (uint32_t)f2bf(p[2]) | ((uint32_t)f2bf(p[3]) << 16);
    *(u32x2*)(els + r * ROWU + lofs) = pp;
  }

  f32x4 oA[4] = {{0.f,0.f,0.f,0.f},{0.f,0.f,0.f,0.f},{0.f,0.f,0.f,0.f},{0.f,0.f,0.f,0.f}};
#pragma unroll
  for (int gi = 0; gi < NT / 2; ++gi) {
    union { u32x4 u; bf16x8 v8; } pu;
    pu.u = *(const u32x4*)(els + fr * ROWU + (swzb((cbase + 32 * gi + 8 * kg) * 2) >> 2));
    const bf16x8 pa = pu.v8;
    const int kk = cbase + gi * 32 + kg * 8;
    if constexpr (WS) {
      const u16* vp = vt + ((size_t)(b * ND + fr)) * NL + kk;
      oA[0] = MFMA(pa, *(const bf16x8*)(vp),           oA[0], 0, 0, 0);
      oA[1] = MFMA(pa, *(const bf16x8*)(vp + 16 * NL), oA[1], 0, 0, 0);
      oA[2] = MFMA(pa, *(const bf16x8*)(vp + 32 * NL), oA[2], 0, 0, 0);
      oA[3] = MFMA(pa, *(const bf16x8*)(vp + 48 * NL), oA[3], 0, 0, 0);
    } else {
#pragma unroll
      for (int dt = 0; dt < 4; ++dt) {
        bf16x8 vf;
#pragma unroll
        for (int i = 0; i < 8; ++i)
          vf[i] = (short)f2bf(v[((size_t)(b * NL + kk + i)) * ND + dt * 16 + fr]);
        oA[dt] = MFMA(pa, vf, oA[dt], 0, 0, 0);
      }
    }
  }
  __syncthreads();

  float* osta = (float*)els;
  f32x4 acc = {0.f, 0.f, 0.f, 0.f};
  const int rrr = tid >> 4;
  const int d4 = (tid & 15) * 4;
#pragma unroll
  for (int round = 0; round < NW / 2; ++round) {
    if ((w >> 1) == round) {
      float* od = osta + (w & 1) * (QT * ND);
#pragma unroll
      for (int dt = 0; dt < 4; ++dt)
#pragma unroll
        for (int j = 0; j < 4; ++j)
          od[(4 * kg + j) * ND + dt * 16 + fr] = oA[dt][j];
    }
    __syncthreads();
    if (tid < QT * ND / 4) {
      acc += *(const f32x4*)(osta + rrr * ND + d4) +
             *(const f32x4*)(osta + QT * ND + rrr * ND + d4);
    }
    __syncthreads();
  }
  if (tid < QT * ND / 4)
    *(f32x4*)(out + (bq + rrr) * ND + d4) = acc;
}

__global__ void __launch_bounds__(NTHREADS, 4)
attn_ws(const float* __restrict__ q, const float* __restrict__ k,
        const float* __restrict__ v, const float* __restrict__ ew,
        const u16* __restrict__ qs, const u16* __restrict__ kb,
        const u16* __restrict__ vt, const uint32_t* __restrict__ mb,
        float* __restrict__ out, float* __restrict__ attn) {
  extern __shared__ uint32_t els[];
  __shared__ float rsums[NW * QT];
  attn_core<0, true>(q, k, v, ew, nullptr, qs, kb, vt, mb, out, attn, els, rsums);
}

__global__ void __launch_bounds__(NTHREADS, 4)
attn_fb(const float* __restrict__ q, const float* __restrict__ k,
        const float* __restrict__ v, const float* __restrict__ ew,
        const void* __restrict__ mask,
        float* __restrict__ out, float* __restrict__ attn) {
  extern __shared__ uint32_t els[];
  __shared__ float rsums[NW * QT];
  __shared__ int s_mode;
  if (threadIdx.x < 64) {
    const uint32_t x = ((const uint32_t*)mask)[threadIdx.x];
    const int all01 = __all(x <= 1u);
    const int allf  = __all(x == 0u || x == 0x3F800000u);
    const int oddz  = __all(((threadIdx.x & 1) == 0) || (x == 0u));
    if (threadIdx.x == 0) s_mode = all01 ? (oddz ? 3 : 0) : (allf ? 2 : 1);
  }
  __syncthreads();
  switch (s_mode) {
    case 0:  attn_core<0, false>(q, k, v, ew, mask, nullptr, nullptr, nullptr, nullptr, out, attn, els, rsums); break;
    case 1:  attn_core<1, false>(q, k, v, ew, mask, nullptr, nullptr, nullptr, nullptr, out, attn, els, rsums); break;
    case 2:  attn_core<2, false>(q, k, v, ew, mask, nullptr, nullptr, nullptr, nullptr, out, attn, els, rsums); break;
    default: attn_core<3, false>(q, k, v, ew, mask, nullptr, nullptr, nullptr, nullptr, out, attn, els, rsums); break;
  }
}

// ---------------- preps ----------------
// merged: q*0.125 + k -> bf16 ws (first QKB blocks) ; mask -> bitpack (rest)
#define QKB ((unsigned)(2 * QEC / 4 / 256))
__global__ void __launch_bounds__(256)
prep_a(const float* __restrict__ q, const float* __restrict__ k,
       u16* __restrict__ qs, u16* __restrict__ kb,
       const void* __restrict__ mask, uint32_t* __restrict__ mb) {
  if (blockIdx.x < QKB) {
    const size_t NQ4 = (size_t)QEC / 4;
    const size_t i = (size_t)blockIdx.x * 256 + threadIdx.x;
    f32x4 val;
    u16* dst;
    if (i < NQ4) {
      val = ((const f32x4*)q)[i];
      val *= 0.125f;
      dst = qs + i * 4;
    } else {
      val = ((const f32x4*)k)[i - NQ4];
      dst = kb + (i - NQ4) * 4;
    }
    u16x4 o;
#pragma unroll
    for (int j = 0; j < 4; ++j) o[j] = f2bf(val[j]);
    *(u16x4*)dst = o;
    return;
  }
  __shared__ int pm;
  if (threadIdx.x < 64) {
    const uint32_t x = ((const uint32_t*)mask)[threadIdx.x];
    const int all01 = __all(x <= 1u);
    const int allf  = __all(x == 0u || x == 0x3F800000u);
    const int oddz  = __all(((threadIdx.x & 1) == 0) || (x == 0u));
    if (threadIdx.x == 0) pm = all01 ? (oddz ? 3 : 0) : (allf ? 2 : 1);
  }
  __syncthreads();
  const int mode = pm;
  const size_t t = (size_t)(blockIdx.x - QKB) * 256 + threadIdx.x;
  uint32_t bits = 0;
  if (mode == 1) {
    const u32x4 x0 = *(((const u32x4*)mask) + t * 2);
    const u32x4 x1 = *(((const u32x4*)mask) + t * 2 + 1);
#pragma unroll
    for (int i = 0; i < 4; ++i)
#pragma unroll
      for (int by = 0; by < 4; ++by) {
        bits |= (((x0[i] >> (8 * by)) & 0xFFu) ? 1u : 0u) << (i * 4 + by);
        bits |= (((x1[i] >> (8 * by)) & 0xFFu) ? 1u : 0u) << (16 + i * 4 + by);
      }
  } else if (mode == 0 || mode == 2) {
#pragma unroll
    for (int c = 0; c < 8; ++c) {
      const u32x4 x = *(((const u32x4*)mask) + t * 8 + c);
#pragma unroll
      for (int i = 0; i < 4; ++i) bits |= (x[i] ? 1u : 0u) << (c * 4 + i);
    }
  } else {
    const uint32_t* p = (const uint32_t*)mask;
#pragma unroll
    for (int i = 0; i < 32; ++i) bits |= (p[2 * (t * 32 + i)] ? 1u : 0u) << i;
  }
  mb[t] = bits;
}

// prep: v -> bf16 V^T (per-batch 64x2048)
__global__ void __launch_bounds__(256)
prep_vt(const float* __restrict__ v, u16* __restrict__ vt) {
  __shared__ float t[64 * 68];
  const int b = blockIdx.y;
  const int k0 = blockIdx.x * 64;
  const int tid = threadIdx.x;
  const int rr = tid >> 4;
  const int c4 = (tid & 15) * 4;
#pragma unroll
  for (int i = 0; i < 4; ++i) {
    const int r = rr + 16 * i;
    const f32x4 val = *(const f32x4*)(v + ((size_t)(b * NL + k0 + r)) * ND + c4);
    *(f32x4*)(t + r * 68 + c4) = val;
  }
  __syncthreads();
#pragma unroll
  for (int i = 0; i < 4; ++i) {
    const int d = rr + 16 * i;
    u16x4 o;
#pragma unroll
    for (int j = 0; j < 4; ++j) o[j] = f2bf(t[(c4 + j) * 68 + d]);
    *(u16x4*)(vt + ((size_t)(b * ND + d)) * NL + k0 + c4) = o;
  }
}

extern "C" void kernel_launch(void* const* d_in, const int* in_sizes, int n_in,
                              void* d_out, int out_size, void* d_ws, size_t ws_size,
                              hipStream_t stream) {
  const float* q    = (const float*)d_in[0];
  const float* k    = (const float*)d_in[1];
  const float* v    = (const float*)d_in[2];
  const float* ew   = (const float*)d_in[3];
  const void*  mask = d_in[4];
  float* out  = (float*)d_out;
  float* attn = out + (size_t)NB * NL * ND;

  const size_t QE = (size_t)QEC;
  const size_t MBW = (size_t)NB * NL * (NL / 32);
  u16* qs = (u16*)d_ws;
  u16* kb = qs + QE;
  u16* vt = kb + QE;
  uint32_t* mb = (uint32_t*)(vt + QE);
  float* invw = (float*)(mb + MBW);
  u16* ews = (u16*)(invw + (size_t)NB * NL);

  const size_t need_base  = 3 * QE * sizeof(u16) + MBW * sizeof(uint32_t);
  const size_t need_split = need_base + (size_t)NB * NL * sizeof(float) +
                            (size_t)NB * NL * NL * sizeof(u16);

  (void)hipFuncSetAttribute(reinterpret_cast<const void*>(attn_e),
                            hipFuncAttributeMaxDynamicSharedMemorySize, LDSB);
  (void)hipFuncSetAttribute(reinterpret_cast<const void*>(attn_spv),
                            hipFuncAttributeMaxDynamicSharedMemorySize, LDSB);
  (void)hipFuncSetAttribute(reinterpret_cast<const void*>(attn_ws),
                            hipFuncAttributeMaxDynamicSharedMemorySize, LDSB);
  (void)hipFuncSetAttribute(reinterpret_cast<const void*>(attn_fb),
                            hipFuncAttributeMaxDynamicSharedMemorySize, LDSB);

  dim3 grid(NB * (NL / QT));
  if (ws_size >= need_split) {
    prep_a<<<dim3(QKB + (unsigned)(MBW / 256)), 256, 0, stream>>>(q, k, qs, kb, mask, mb);
    prep_vt<<<dim3(NL / 64, NB), 256, 0, stream>>>(v, vt);
    attn_e<<<grid, NTHREADS, LDSB, stream>>>(qs, kb, mb, ews, invw);
    attn_spv<<<grid, NTHREADS, LDSB, stream>>>(ews, invw, ew, vt, out, attn);
  } else if (ws_size >= need_base) {
    prep_a<<<dim3(QKB + (unsigned)(MBW / 256)), 256, 0, stream>>>(q, k, qs, kb, mask, mb);
    prep_vt<<<dim3(NL / 64, NB), 256, 0, stream>>>(v, vt);
    attn_ws<<<grid, NTHREADS, LDSB, stream>>>(q, k, v, ew, qs, kb, vt, mb, out, attn);
  } else {
    attn_fb<<<grid, NTHREADS, LDSB, stream>>>(q, k, v, ew, mask, out, attn);
  }
}

// Round 17
// 240.963 us; speedup vs baseline: 1.2083x; 1.2083x over previous
//
#include <hip/hip_runtime.h>
#include <cstdint>
#include <cstddef>

#define NB 16
#define NL 2048
#define ND 64
#define QT 16                 // q rows per workgroup
#define NW 8                  // waves per workgroup
#define NTHREADS (NW * 64)
#define SLICE (NL / NW)       // 256 k-cols per wave
#define NT (SLICE / 16)       // 16 MFMA col-tiles per wave
#define ROWU 1026             // u32 per padded LDS row (4104 B)
#define ELSU (QT * ROWU)      // 16416 u32 = 65664 B
#define LDSB (ELSU * 4)
#define QEC (NB * NL * ND)    // 2M elems per q/k/v matrix

typedef __attribute__((ext_vector_type(8))) short bf16x8;
typedef __attribute__((ext_vector_type(4))) float f32x4;
typedef __attribute__((ext_vector_type(4))) int i32x4;
typedef __attribute__((ext_vector_type(4))) unsigned short u16x4;
typedef __attribute__((ext_vector_type(2))) unsigned int u32x2;
typedef __attribute__((ext_vector_type(4))) unsigned int u32x4;
typedef unsigned short u16;

#define MFMA __builtin_amdgcn_mfma_f32_16x16x32_bf16

__device__ __forceinline__ u16 f2bf(float x) {
  union { float f; uint32_t u; } v; v.f = x;
  uint32_t r = v.u + 0x7FFFu + ((v.u >> 16) & 1u);   // RNE
  return (u16)(r >> 16);
}
__device__ __forceinline__ float bfhi2f(uint32_t w) {
  union { uint32_t u; float f; } v; v.u = w & 0xFFFF0000u; return v.f;
}
__device__ __forceinline__ float bflo2f(uint32_t w) {
  union { uint32_t u; float f; } v; v.u = w << 16; return v.f;
}
// XOR-swizzle byte offset within a 4096B LDS row (keeps 16B alignment)
__device__ __forceinline__ int swzb(int cb) { return cb ^ (((cb >> 7) & 7) << 4); }

// mask nibble (fallback path). MODE: 0=i32,1=u8,2=f32,3=i64
template <int MODE>
__device__ __forceinline__ uint32_t mnib(const void* __restrict__ m, size_t i) {
  if constexpr (MODE == 1) {
    const uint32_t x = __builtin_nontemporal_load((const uint32_t*)((const uint8_t*)m + i));
    return (x | (x >> 7) | (x >> 14) | (x >> 21)) & 0xFu;
  } else if constexpr (MODE == 0) {
    const i32x4 x = __builtin_nontemporal_load(((const i32x4*)((const int*)m + i)));
    return (uint32_t)(x[0] != 0) | ((uint32_t)(x[1] != 0) << 1) |
           ((uint32_t)(x[2] != 0) << 2) | ((uint32_t)(x[3] != 0) << 3);
  } else if constexpr (MODE == 2) {
    const f32x4 x = __builtin_nontemporal_load(((const f32x4*)((const float*)m + i)));
    return (uint32_t)(x[0] != 0.f) | ((uint32_t)(x[1] != 0.f) << 1) |
           ((uint32_t)(x[2] != 0.f) << 2) | ((uint32_t)(x[3] != 0.f) << 3);
  } else {
    const uint32_t* p = (const uint32_t*)m + 2 * i;
    return (uint32_t)(p[0] != 0u) | ((uint32_t)(p[2] != 0u) << 1) |
           ((uint32_t)(p[4] != 0u) << 2) | ((uint32_t)(p[6] != 0u) << 3);
  }
}

template <bool WS>
__device__ __forceinline__ void loadKfrag(const float* __restrict__ k,
                                          const u16* __restrict__ kb,
                                          int b, int row, int kg,
                                          bf16x8& b0, bf16x8& b1) {
  if constexpr (WS) {
    const u16* kp = kb + ((size_t)(b * NL + row)) * ND + kg * 8;
    b0 = *(const bf16x8*)kp;
    b1 = *(const bf16x8*)(kp + 32);
  } else {
    const float* kp = k + ((size_t)(b * NL + row)) * ND + kg * 8;
#pragma unroll
    for (int i = 0; i < 8; ++i) {
      b0[i] = (short)f2bf(kp[i]);
      b1[i] = (short)f2bf(kp[i + 32]);
    }
  }
}

template <int MMODE, bool WS>
__device__ __forceinline__ void attn_core(
    const float* __restrict__ q, const float* __restrict__ k,
    const float* __restrict__ v, const float* __restrict__ ew,
    const void* __restrict__ mask,
    const u16* __restrict__ qs, const u16* __restrict__ kb,
    const u16* __restrict__ vt, const uint32_t* __restrict__ mb,
    float* __restrict__ out, float* __restrict__ attn,
    uint32_t* __restrict__ els, float* __restrict__ rsums) {
  const int tid = threadIdx.x;
  const int lane = tid & 63;
  const int w = tid >> 6;
  const int fr = lane & 15;
  const int kg = lane >> 4;

  // XCD-aware bijective swizzle
  const int bid = blockIdx.x;
  const int swzid = (bid & 7) * ((NB * (NL / QT)) / 8) + (bid >> 3);
  const int b = swzid >> 7;
  const int q0 = (swzid & 127) * QT;
  const int cbase = w * SLICE;
  const size_t bq = (size_t)b * NL + q0;
  const size_t lrow = bq * NL + (size_t)fr * NL + (size_t)(cbase + 4 * kg);

  // Q fragments (temperature folded in)
  bf16x8 a0, a1;
  if constexpr (WS) {
    const u16* qp = qs + (bq + fr) * ND + kg * 8;
    a0 = *(const bf16x8*)qp;
    a1 = *(const bf16x8*)(qp + 32);
  } else {
    const float* qp = q + (bq + fr) * ND + kg * 8;
#pragma unroll
    for (int i = 0; i < 8; ++i) {
      a0[i] = (short)f2bf(qp[i] * 0.125f);
      a1[i] = (short)f2bf(qp[i + 32] * 0.125f);
    }
  }

  // mask bit-words for this lane's (row fr, 256-col slice)
  uint32_t mw[8];
  if constexpr (WS) {
    const uint32_t* mbr = mb + (bq + fr) * (NL / 32) + (cbase >> 5);
#pragma unroll
    for (int u = 0; u < 8; ++u) mw[u] = mbr[u];
  }

  // ---- Phase A: S^T = mfma(K,Q); e = exp(masked S) -> own swizzled LDS slice ----
  float rs = 0.f;
#pragma unroll
  for (int ti = 0; ti < NT; ++ti) {
    const int c0 = cbase + ti * 16;
    bf16x8 b0, b1;
    loadKfrag<WS>(k, kb, b, c0 + fr, kg, b0, b1);
    f32x4 s = {0.f, 0.f, 0.f, 0.f};
    s = MFMA(b0, a0, s, 0, 0, 0);   // lane holds S[q=fr][k=c0+4kg+j]
    s = MFMA(b1, a1, s, 0, 0, 0);
    uint32_t nib;
    if constexpr (WS) nib = (mw[ti >> 1] >> (16 * (ti & 1) + 4 * kg)) & 0xFu;
    else              nib = mnib<MMODE>(mask, lrow + (size_t)(ti * 16));
    const float e0 = (nib & 1u) ? 0.f : __expf(s[0]);
    const float e1 = (nib & 2u) ? 0.f : __expf(s[1]);
    const float e2 = (nib & 4u) ? 0.f : __expf(s[2]);
    const float e3 = (nib & 8u) ? 0.f : __expf(s[3]);
    rs += (e0 + e1) + (e2 + e3);
    u32x2 ep;
    ep[0] = (uint32_t)f2bf(e0) | ((uint32_t)f2bf(e1) << 16);
    ep[1] = (uint32_t)f2bf(e2) | ((uint32_t)f2bf(e3) << 16);
    *(u32x2*)(els + fr * ROWU + (swzb((c0 + 4 * kg) * 2) >> 2)) = ep;
  }
  rs += __shfl_xor(rs, 16, 64);
  rs += __shfl_xor(rs, 32, 64);
  if (lane < 16) rsums[w * QT + fr] = rs;
  __syncthreads();   // the ONLY cross-wave sync before the epilogue

  // per-lane inv for row fr (lanes 0..15 hold rows 0..15)
  float invf = 0.f;
#pragma unroll
  for (int ww = 0; ww < NW; ++ww) invf += rsums[ww * QT + fr];
  invf = 1.0f / invf;

  // ---- Phase B1a: LOAD-ONLY streaming. ew load -> p -> p̂ into LDS.
  // No global stores here: vmcnt tracks only loads, so the compiler's
  // counted waits give real pipeline depth instead of draining stores.
  const float* ewb = ew + bq * NL + cbase + 4 * lane;
  const int lofs = swzb((cbase + 4 * lane) * 2) >> 2;   // col-dependent only
#pragma unroll
  for (int r = 0; r < 16; ++r) {
    const f32x4 w4 = __builtin_nontemporal_load((const f32x4*)(ewb + (size_t)r * NL));
    const u32x2 el = *(const u32x2*)(els + r * ROWU + lofs);
    const float inv_r = __shfl(invf, r, 64);
    u32x2 pp;
    pp[0] = (uint32_t)f2bf(bflo2f(el[0]) * inv_r * w4[0]) |
            ((uint32_t)f2bf(bfhi2f(el[0]) * inv_r * w4[1]) << 16);
    pp[1] = (uint32_t)f2bf(bflo2f(el[1]) * inv_r * w4[2]) |
            ((uint32_t)f2bf(bfhi2f(el[1]) * inv_r * w4[3]) << 16);
    *(u32x2*)(els + r * ROWU + lofs) = pp;
  }

  // ---- Phase B2: PV MFMA, P from own LDS slice (no barrier needed) ----
  f32x4 oA[4] = {{0.f,0.f,0.f,0.f},{0.f,0.f,0.f,0.f},{0.f,0.f,0.f,0.f},{0.f,0.f,0.f,0.f}};
#pragma unroll
  for (int gi = 0; gi < NT / 2; ++gi) {
    union { u32x4 u; bf16x8 v8; } pu;
    pu.u = *(const u32x4*)(els + fr * ROWU + (swzb((cbase + 32 * gi + 8 * kg) * 2) >> 2));
    const bf16x8 pa = pu.v8;
    const int kk = cbase + gi * 32 + kg * 8;
    if constexpr (WS) {
      const u16* vp = vt + ((size_t)(b * ND + fr)) * NL + kk;   // VT[d][k]
      oA[0] = MFMA(pa, *(const bf16x8*)(vp),           oA[0], 0, 0, 0);
      oA[1] = MFMA(pa, *(const bf16x8*)(vp + 16 * NL), oA[1], 0, 0, 0);
      oA[2] = MFMA(pa, *(const bf16x8*)(vp + 32 * NL), oA[2], 0, 0, 0);
      oA[3] = MFMA(pa, *(const bf16x8*)(vp + 48 * NL), oA[3], 0, 0, 0);
    } else {
#pragma unroll
      for (int dt = 0; dt < 4; ++dt) {
        bf16x8 vf;
#pragma unroll
        for (int i = 0; i < 8; ++i)
          vf[i] = (short)f2bf(v[((size_t)(b * NL + kk + i)) * ND + dt * 16 + fr]);
        oA[dt] = MFMA(pa, vf, oA[dt], 0, 0, 0);
      }
    }
  }

  // ---- Phase B1b: STORE-ONLY streaming of attn from LDS p̂.
  // Pure stores are fire-and-forget (fillBuffer measured ~7 TB/s); they
  // drain under the epilogue barriers.
  float* atb = attn + bq * NL + cbase + 4 * lane;
#pragma unroll
  for (int r = 0; r < 16; ++r) {
    const u32x2 pp = *(const u32x2*)(els + r * ROWU + lofs);
    f32x4 p;
    p[0] = bflo2f(pp[0]);
    p[1] = bfhi2f(pp[0]);
    p[2] = bflo2f(pp[1]);
    p[3] = bfhi2f(pp[1]);
    __builtin_nontemporal_store(p, (f32x4*)(atb + (size_t)r * NL));
  }
  __syncthreads();   // all LDS p-reads done; safe to reuse els as out-staging

  // ---- 4-round staged cross-wave out reduction (osta aliases els) ----
  float* osta = (float*)els;
  f32x4 acc = {0.f, 0.f, 0.f, 0.f};
  const int rrr = tid >> 4;
  const int d4 = (tid & 15) * 4;
#pragma unroll
  for (int round = 0; round < NW / 2; ++round) {
    if ((w >> 1) == round) {
      float* od = osta + (w & 1) * (QT * ND);
#pragma unroll
      for (int dt = 0; dt < 4; ++dt)
#pragma unroll
        for (int j = 0; j < 4; ++j)
          od[(4 * kg + j) * ND + dt * 16 + fr] = oA[dt][j];
    }
    __syncthreads();
    if (tid < QT * ND / 4) {
      acc += *(const f32x4*)(osta + rrr * ND + d4) +
             *(const f32x4*)(osta + QT * ND + rrr * ND + d4);
    }
    __syncthreads();
  }
  if (tid < QT * ND / 4)
    *(f32x4*)(out + (bq + rrr) * ND + d4) = acc;
}

__global__ void __launch_bounds__(NTHREADS, 4)
attn_ws(const float* __restrict__ q, const float* __restrict__ k,
        const float* __restrict__ v, const float* __restrict__ ew,
        const u16* __restrict__ qs, const u16* __restrict__ kb,
        const u16* __restrict__ vt, const uint32_t* __restrict__ mb,
        float* __restrict__ out, float* __restrict__ attn) {
  extern __shared__ uint32_t els[];
  __shared__ float rsums[NW * QT];
  attn_core<0, true>(q, k, v, ew, nullptr, qs, kb, vt, mb, out, attn, els, rsums);
}

__global__ void __launch_bounds__(NTHREADS, 4)
attn_fb(const float* __restrict__ q, const float* __restrict__ k,
        const float* __restrict__ v, const float* __restrict__ ew,
        const void* __restrict__ mask,
        float* __restrict__ out, float* __restrict__ attn) {
  extern __shared__ uint32_t els[];
  __shared__ float rsums[NW * QT];
  __shared__ int s_mode;
  if (threadIdx.x < 64) {
    const uint32_t x = ((const uint32_t*)mask)[threadIdx.x];
    const int all01 = __all(x <= 1u);
    const int allf  = __all(x == 0u || x == 0x3F800000u);
    const int oddz  = __all(((threadIdx.x & 1) == 0) || (x == 0u));
    if (threadIdx.x == 0) s_mode = all01 ? (oddz ? 3 : 0) : (allf ? 2 : 1);
  }
  __syncthreads();
  switch (s_mode) {
    case 0:  attn_core<0, false>(q, k, v, ew, mask, nullptr, nullptr, nullptr, nullptr, out, attn, els, rsums); break;
    case 1:  attn_core<1, false>(q, k, v, ew, mask, nullptr, nullptr, nullptr, nullptr, out, attn, els, rsums); break;
    case 2:  attn_core<2, false>(q, k, v, ew, mask, nullptr, nullptr, nullptr, nullptr, out, attn, els, rsums); break;
    default: attn_core<3, false>(q, k, v, ew, mask, nullptr, nullptr, nullptr, nullptr, out, attn, els, rsums); break;
  }
}

// ---------------- preps ----------------
// merged: q*0.125 + k -> bf16 ws (first QKB blocks) ; mask -> bitpack (rest)
#define QKB ((unsigned)(2 * QEC / 4 / 256))
__global__ void __launch_bounds__(256)
prep_a(const float* __restrict__ q, const float* __restrict__ k,
       u16* __restrict__ qs, u16* __restrict__ kb,
       const void* __restrict__ mask, uint32_t* __restrict__ mb) {
  if (blockIdx.x < QKB) {
    const size_t NQ4 = (size_t)QEC / 4;
    const size_t i = (size_t)blockIdx.x * 256 + threadIdx.x;
    f32x4 val;
    u16* dst;
    if (i < NQ4) {
      val = ((const f32x4*)q)[i];
      val *= 0.125f;
      dst = qs + i * 4;
    } else {
      val = ((const f32x4*)k)[i - NQ4];
      dst = kb + (i - NQ4) * 4;
    }
    u16x4 o;
#pragma unroll
    for (int j = 0; j < 4; ++j) o[j] = f2bf(val[j]);
    *(u16x4*)dst = o;
    return;
  }
  __shared__ int pm;
  if (threadIdx.x < 64) {
    const uint32_t x = ((const uint32_t*)mask)[threadIdx.x];
    const int all01 = __all(x <= 1u);
    const int allf  = __all(x == 0u || x == 0x3F800000u);
    const int oddz  = __all(((threadIdx.x & 1) == 0) || (x == 0u));
    if (threadIdx.x == 0) pm = all01 ? (oddz ? 3 : 0) : (allf ? 2 : 1);
  }
  __syncthreads();
  const int mode = pm;
  const size_t t = (size_t)(blockIdx.x - QKB) * 256 + threadIdx.x;
  uint32_t bits = 0;
  if (mode == 1) {
    const u32x4 x0 = *(((const u32x4*)mask) + t * 2);
    const u32x4 x1 = *(((const u32x4*)mask) + t * 2 + 1);
#pragma unroll
    for (int i = 0; i < 4; ++i)
#pragma unroll
      for (int by = 0; by < 4; ++by) {
        bits |= (((x0[i] >> (8 * by)) & 0xFFu) ? 1u : 0u) << (i * 4 + by);
        bits |= (((x1[i] >> (8 * by)) & 0xFFu) ? 1u : 0u) << (16 + i * 4 + by);
      }
  } else if (mode == 0 || mode == 2) {
#pragma unroll
    for (int c = 0; c < 8; ++c) {
      const u32x4 x = *(((const u32x4*)mask) + t * 8 + c);
#pragma unroll
      for (int i = 0; i < 4; ++i) bits |= (x[i] ? 1u : 0u) << (c * 4 + i);
    }
  } else {
    const uint32_t* p = (const uint32_t*)mask;
#pragma unroll
    for (int i = 0; i < 32; ++i) bits |= (p[2 * (t * 32 + i)] ? 1u : 0u) << i;
  }
  mb[t] = bits;
}

// prep: v -> bf16 V^T (per-batch 64x2048)
__global__ void __launch_bounds__(256)
prep_vt(const float* __restrict__ v, u16* __restrict__ vt) {
  __shared__ float t[64 * 68];
  const int b = blockIdx.y;
  const int k0 = blockIdx.x * 64;
  const int tid = threadIdx.x;
  const int rr = tid >> 4;
  const int c4 = (tid & 15) * 4;
#pragma unroll
  for (int i = 0; i < 4; ++i) {
    const int r = rr + 16 * i;
    const f32x4 val = *(const f32x4*)(v + ((size_t)(b * NL + k0 + r)) * ND + c4);
    *(f32x4*)(t + r * 68 + c4) = val;
  }
  __syncthreads();
#pragma unroll
  for (int i = 0; i < 4; ++i) {
    const int d = rr + 16 * i;
    u16x4 o;
#pragma unroll
    for (int j = 0; j < 4; ++j) o[j] = f2bf(t[(c4 + j) * 68 + d]);
    *(u16x4*)(vt + ((size_t)(b * ND + d)) * NL + k0 + c4) = o;
  }
}

extern "C" void kernel_launch(void* const* d_in, const int* in_sizes, int n_in,
                              void* d_out, int out_size, void* d_ws, size_t ws_size,
                              hipStream_t stream) {
  const float* q    = (const float*)d_in[0];
  const float* k    = (const float*)d_in[1];
  const float* v    = (const float*)d_in[2];
  const float* ew   = (const float*)d_in[3];
  const void*  mask = d_in[4];
  float* out  = (float*)d_out;
  float* attn = out + (size_t)NB * NL * ND;

  const size_t QE = (size_t)QEC;
  const size_t MBW = (size_t)NB * NL * (NL / 32);
  u16* qs = (u16*)d_ws;
  u16* kb = qs + QE;
  u16* vt = kb + QE;
  uint32_t* mb = (uint32_t*)(vt + QE);

  const size_t need_base = 3 * QE * sizeof(u16) + MBW * sizeof(uint32_t);

  (void)hipFuncSetAttribute(reinterpret_cast<const void*>(attn_ws),
                            hipFuncAttributeMaxDynamicSharedMemorySize, LDSB);
  (void)hipFuncSetAttribute(reinterpret_cast<const void*>(attn_fb),
                            hipFuncAttributeMaxDynamicSharedMemorySize, LDSB);

  dim3 grid(NB * (NL / QT));   // 2048, 1-D for XCD swizzle
  if (ws_size >= need_base) {
    prep_a<<<dim3(QKB + (unsigned)(MBW / 256)), 256, 0, stream>>>(q, k, qs, kb, mask, mb);
    prep_vt<<<dim3(NL / 64, NB), 256, 0, stream>>>(v, vt);
    attn_ws<<<grid, NTHREADS, LDSB, stream>>>(q, k, v, ew, qs, kb, vt, mb, out, attn);
  } else {
    attn_fb<<<grid, NTHREADS, LDSB, stream>>>(q, k, v, ew, mask, out, attn);
  }
}